// Round 4
// baseline (597.026 us; speedup 1.0000x reference)
//
#include <hip/hip_runtime.h>

// EMA energy normalizer: mag [B,F,T] fp32 -> (mag_norm [B,F,T], mag_mean [B,1,T])
//
// R8: ONE-PASS linear kernel. Evidence so far:
//  - R6: flag/spin decoupled protocol is correct (passed), but columnar 96B
//    gathers run at 0.6 TB/s -> 352us.
//  - R7: all-linear 3-kernel = 206us total, of which ~130us is harness
//    re-poison fills (387MB @6.5TB/s, visible in counters) -> ours ~73us.
//    Slack: mag read twice + 2 kernel drains + latency-bound KRS.
// R8 merges them: linear loads, 8 rows/block HELD IN REGISTERS (24 float4/thr),
// partial rows + flag1 (release/acquire at agent scope flushes/invalidates the
// non-coherent XCD L2s), per-batch scan block -> recip + flag2, siblings
// normalize from registers. mag read ONCE. ws: 12.7MB, runtime fallback to
// the proven R7 pipeline if ws is smaller.

#define B_   32
#define F_   257
#define T_   3000
#define T4   750          // float4s per row
#define MOM  0.99f
#define OMM  0.01f
#define EPS_ 1e-8f
#define INVF (1.0f / 257.0f)

#define ACC4(a, v) { a.x += v.x; a.y += v.y; a.z += v.z; a.w += v.w; }

__device__ inline void wait_flag(const unsigned* p) {
    while (__hip_atomic_load(p, __ATOMIC_ACQUIRE, __HIP_MEMORY_SCOPE_AGENT) == 0u)
        __builtin_amdgcn_s_sleep(4);
}

// ---------------------------------------------------------------------------
// Fused one-pass kernel. 1024 blocks = (b, ch<32). Rows f0=ch*8 .. f0+7 held
// in registers; ch==31 additionally streams row 256; ch==0 is the scan block.
// ---------------------------------------------------------------------------
__global__ __launch_bounds__(256) void ema_onepass(
    const float* __restrict__ mag,
    const float* __restrict__ bias,
    const float* __restrict__ rmean,
    float* __restrict__ out,
    float* __restrict__ mag_mean,
    unsigned* __restrict__ flag1,      // [B_*32]
    unsigned* __restrict__ flag2,      // [B_]
    float* __restrict__ partial,       // [B_][32][T_]
    float* __restrict__ recip)         // [B_][T_]
{
    __shared__ float4 xs4[T4];         // 12 KB (scan block: means -> recips)
    float* xs = reinterpret_cast<float*>(xs4);
    __shared__ float sA[256];
    __shared__ float sB[256];

    const int blk = blockIdx.x;        // b*32 + ch
    const int b   = blk >> 5;
    const int ch  = blk & 31;
    const int tid = threadIdx.x;
    const bool c2 = tid < (T4 - 512);  // tid < 238 owns a third float4 column

    // ---- phase A: load 8 full rows linearly into registers, column-reduce
    const float4* magv = reinterpret_cast<const float4*>(mag)
                       + (size_t)(b * F_ + ch * 8) * T4;
    float4 r[8][3];
    float4 a0 = make_float4(0.f,0.f,0.f,0.f);
    float4 a1 = make_float4(0.f,0.f,0.f,0.f);
    float4 a2 = make_float4(0.f,0.f,0.f,0.f);
    #pragma unroll
    for (int i = 0; i < 8; ++i) {
        r[i][0] = magv[(size_t)i * T4 + tid];
        r[i][1] = magv[(size_t)i * T4 + tid + 256];
        ACC4(a0, r[i][0]);
        ACC4(a1, r[i][1]);
        if (c2) { r[i][2] = magv[(size_t)i * T4 + tid + 512]; ACC4(a2, r[i][2]); }
    }
    if (ch == 31) {                    // stream row 256 into the reduction only
        float4 v0 = magv[(size_t)8 * T4 + tid];
        float4 v1 = magv[(size_t)8 * T4 + tid + 256];
        ACC4(a0, v0); ACC4(a1, v1);
        if (c2) { float4 v2 = magv[(size_t)8 * T4 + tid + 512]; ACC4(a2, v2); }
    }

    {   // publish partial row (linear 12 KB) + flag1 (release flushes L2)
        float4* pv = reinterpret_cast<float4*>(partial) + (size_t)blk * T4;
        pv[tid]       = a0;
        pv[tid + 256] = a1;
        if (c2) pv[tid + 512] = a2;
    }
    __syncthreads();                   // drains vmcnt: all stores in L2
    if (tid == 0)
        __hip_atomic_store(&flag1[blk], 1u, __ATOMIC_RELEASE,
                           __HIP_MEMORY_SCOPE_AGENT);

    if (ch == 0) {
        // ---- phase B (scan block): wait 32 sibling partials, reduce, scan
        if (tid < 32) wait_flag(&flag1[b * 32 + tid]);
        __syncthreads();

        const float4* pv = reinterpret_cast<const float4*>(partial)
                         + (size_t)b * 32 * T4;
        float4 s0 = make_float4(0.f,0.f,0.f,0.f);
        float4 s1 = make_float4(0.f,0.f,0.f,0.f);
        float4 s2 = make_float4(0.f,0.f,0.f,0.f);
        #pragma unroll 4
        for (int j = 0; j < 32; ++j) {
            const float4* rp = pv + (size_t)j * T4;
            float4 v0 = rp[tid];
            float4 v1 = rp[tid + 256];
            ACC4(s0, v0); ACC4(s1, v1);
            if (c2) { float4 v2 = rp[tid + 512]; ACC4(s2, v2); }
        }
        s0.x *= INVF; s0.y *= INVF; s0.z *= INVF; s0.w *= INVF;
        s1.x *= INVF; s1.y *= INVF; s1.z *= INVF; s1.w *= INVF;
        xs4[tid]       = s0;
        xs4[tid + 256] = s1;
        if (c2) {
            s2.x *= INVF; s2.y *= INVF; s2.z *= INVF; s2.w *= INVF;
            xs4[tid + 512] = s2;
        }
        __syncthreads();

        // local chunk scan: 250 active threads x 12 steps (validated)
        const int CH = 12;
        const int t0 = tid * CH;
        float A = 1.f, Bv = 0.f;
        if (t0 < T_) {
            #pragma unroll
            for (int j = 0; j < CH; ++j) {
                Bv = MOM * Bv + OMM * xs[t0 + j];
                A *= MOM;
            }
        }
        sA[tid] = A; sB[tid] = Bv;
        __syncthreads();

        // Hillis-Steele over affine maps: (Ap,Bp)∘(Ac,Bc) = (Ap*Ac, Bp*Ac+Bc)
        for (int off = 1; off < 256; off <<= 1) {
            float cA = sA[tid], cB = sB[tid];
            float pA = 1.f, pB = 0.f;
            if (tid >= off) { pA = sA[tid - off]; pB = sB[tid - off]; }
            __syncthreads();
            if (tid >= off) { sA[tid] = pA * cA; sB[tid] = pB * cA + cB; }
            __syncthreads();
        }
        float pA = 1.f, pB = 0.f;
        if (tid > 0) { pA = sA[tid - 1]; pB = sB[tid - 1]; }
        __syncthreads();

        const float bias0 = bias[0];
        if (t0 < T_) {
            float m = pA * rmean[0] + pB;        // m_{t0-1}
            #pragma unroll
            for (int j = 0; j < CH; ++j) {
                m = MOM * m + OMM * xs[t0 + j];
                xs[t0 + j] = m + bias0;          // mean + bias
            }
        }
        __syncthreads();

        // emit mag_mean + recip table; flip LDS to recips for own phase C
        float4* mmv = reinterpret_cast<float4*>(mag_mean) + (size_t)b * T4;
        float4* rcv = reinterpret_cast<float4*>(recip)    + (size_t)b * T4;
        for (int i = tid; i < T4; i += 256) {
            float4 v = xs4[i];
            mmv[i] = v;
            float4 rv;
            rv.x = 1.0f / (v.x + EPS_); rv.y = 1.0f / (v.y + EPS_);
            rv.z = 1.0f / (v.z + EPS_); rv.w = 1.0f / (v.w + EPS_);
            rcv[i] = rv;
            xs4[i] = rv;
        }
        __syncthreads();               // drains stores before release
        if (tid == 0)
            __hip_atomic_store(&flag2[b], 1u, __ATOMIC_RELEASE,
                               __HIP_MEMORY_SCOPE_AGENT);
        // recips for phase C come straight from LDS
    }

    // ---- phase C: normalize held rows
    float4 rc0, rc1, rc2;
    if (ch == 0) {
        rc0 = xs4[tid];
        rc1 = xs4[tid + 256];
        rc2 = c2 ? xs4[tid + 512] : rc0;
    } else {
        if (tid == 0) wait_flag(&flag2[b]);
        __syncthreads();               // acquire visible block-wide (same CU)
        const float4* rcv = reinterpret_cast<const float4*>(recip) + (size_t)b * T4;
        rc0 = rcv[tid];
        rc1 = rcv[tid + 256];
        rc2 = c2 ? rcv[tid + 512] : rc0;
    }

    float4* ov = reinterpret_cast<float4*>(out) + (size_t)(b * F_ + ch * 8) * T4;
    #pragma unroll
    for (int i = 0; i < 8; ++i) {
        float4 o;
        float4 v0 = r[i][0];
        o.x = v0.x * rc0.x; o.y = v0.y * rc0.y; o.z = v0.z * rc0.z; o.w = v0.w * rc0.w;
        ov[(size_t)i * T4 + tid] = o;
        float4 v1 = r[i][1];
        o.x = v1.x * rc1.x; o.y = v1.y * rc1.y; o.z = v1.z * rc1.z; o.w = v1.w * rc1.w;
        ov[(size_t)i * T4 + tid + 256] = o;
        if (c2) {
            float4 v2 = r[i][2];
            o.x = v2.x * rc2.x; o.y = v2.y * rc2.y; o.z = v2.z * rc2.z; o.w = v2.w * rc2.w;
            ov[(size_t)i * T4 + tid + 512] = o;
        }
    }
    if (ch == 31) {                    // row 256: re-read (L3-hot), normalize
        float4 o;
        float4 v0 = magv[(size_t)8 * T4 + tid];
        o.x = v0.x * rc0.x; o.y = v0.y * rc0.y; o.z = v0.z * rc0.z; o.w = v0.w * rc0.w;
        ov[(size_t)8 * T4 + tid] = o;
        float4 v1 = magv[(size_t)8 * T4 + tid + 256];
        o.x = v1.x * rc1.x; o.y = v1.y * rc1.y; o.z = v1.z * rc1.z; o.w = v1.w * rc1.w;
        ov[(size_t)8 * T4 + tid + 256] = o;
        if (c2) {
            float4 v2 = magv[(size_t)8 * T4 + tid + 512];
            o.x = v2.x * rc2.x; o.y = v2.y * rc2.y; o.z = v2.z * rc2.z; o.w = v2.w * rc2.w;
            ov[(size_t)8 * T4 + tid + 512] = o;
        }
    }
}

// ===========================================================================
// Fallback pipeline (proven R7, 206us) for small workspaces.
// ===========================================================================
#define NG1  16

__global__ __launch_bounds__(256) void k1_partial(const float* __restrict__ mag,
                                                  float* __restrict__ partial) {
    const int blk = blockIdx.x;
    const int b   = blk >> 4;
    const int g   = blk & 15;
    const int tid = threadIdx.x;
    const bool has2 = tid < (T4 - 512);

    const float4* magv = reinterpret_cast<const float4*>(mag)
                       + ((size_t)(b * F_ + g * 16)) * T4;
    float4 a0 = make_float4(0.f,0.f,0.f,0.f);
    float4 a1 = make_float4(0.f,0.f,0.f,0.f);
    float4 a2 = make_float4(0.f,0.f,0.f,0.f);

    #pragma unroll 4
    for (int r = 0; r < 16; ++r) {
        const float4* row = magv + (size_t)r * T4;
        float4 v0 = row[tid];
        float4 v1 = row[tid + 256];
        ACC4(a0, v0); ACC4(a1, v1);
        if (has2) { float4 v2 = row[tid + 512]; ACC4(a2, v2); }
    }
    if (g == 15) {
        const float4* row = magv + (size_t)16 * T4;
        float4 v0 = row[tid];
        float4 v1 = row[tid + 256];
        ACC4(a0, v0); ACC4(a1, v1);
        if (has2) { float4 v2 = row[tid + 512]; ACC4(a2, v2); }
    }
    float4* pv = reinterpret_cast<float4*>(partial) + (size_t)blk * T4;
    pv[tid]       = a0;
    pv[tid + 256] = a1;
    if (has2) pv[tid + 512] = a2;
}

__global__ __launch_bounds__(256) void k_reduce_scan(const float* __restrict__ src,
                                                     int nrows,
                                                     const float* __restrict__ bias,
                                                     const float* __restrict__ rmean,
                                                     float* __restrict__ recip,
                                                     float* __restrict__ mag_mean) {
    __shared__ float4 xs4[T4];
    float* xs = reinterpret_cast<float*>(xs4);
    __shared__ float sA[256];
    __shared__ float sB[256];

    const int b   = blockIdx.x;
    const int tid = threadIdx.x;
    const bool has2 = tid < (T4 - 512);

    {
        const float4* sv = reinterpret_cast<const float4*>(src)
                         + (size_t)b * nrows * T4;
        float4 a0 = make_float4(0.f,0.f,0.f,0.f);
        float4 a1 = make_float4(0.f,0.f,0.f,0.f);
        float4 a2 = make_float4(0.f,0.f,0.f,0.f);
        #pragma unroll 4
        for (int r = 0; r < nrows; ++r) {
            const float4* row = sv + (size_t)r * T4;
            float4 v0 = row[tid];
            float4 v1 = row[tid + 256];
            ACC4(a0, v0); ACC4(a1, v1);
            if (has2) { float4 v2 = row[tid + 512]; ACC4(a2, v2); }
        }
        a0.x *= INVF; a0.y *= INVF; a0.z *= INVF; a0.w *= INVF;
        a1.x *= INVF; a1.y *= INVF; a1.z *= INVF; a1.w *= INVF;
        xs4[tid]       = a0;
        xs4[tid + 256] = a1;
        if (has2) {
            a2.x *= INVF; a2.y *= INVF; a2.z *= INVF; a2.w *= INVF;
            xs4[tid + 512] = a2;
        }
    }
    __syncthreads();

    const int CH = 12;
    const int t0 = tid * CH;
    float A = 1.f, Bv = 0.f;
    if (t0 < T_) {
        #pragma unroll
        for (int j = 0; j < CH; ++j) {
            Bv = MOM * Bv + OMM * xs[t0 + j];
            A *= MOM;
        }
    }
    sA[tid] = A; sB[tid] = Bv;
    __syncthreads();

    for (int off = 1; off < 256; off <<= 1) {
        float cA = sA[tid], cB = sB[tid];
        float pA = 1.f, pB = 0.f;
        if (tid >= off) { pA = sA[tid - off]; pB = sB[tid - off]; }
        __syncthreads();
        if (tid >= off) { sA[tid] = pA * cA; sB[tid] = pB * cA + cB; }
        __syncthreads();
    }
    float pA = 1.f, pB = 0.f;
    if (tid > 0) { pA = sA[tid - 1]; pB = sB[tid - 1]; }
    __syncthreads();

    const float bias0 = bias[0];
    if (t0 < T_) {
        float m = pA * rmean[0] + pB;
        #pragma unroll
        for (int j = 0; j < CH; ++j) {
            m = MOM * m + OMM * xs[t0 + j];
            xs[t0 + j] = m + bias0;
        }
    }
    __syncthreads();

    float4* mmv = reinterpret_cast<float4*>(mag_mean) + (size_t)b * T4;
    float4* rcv = reinterpret_cast<float4*>(recip)    + (size_t)b * T4;
    for (int i = tid; i < T4; i += 256) {
        float4 v = xs4[i];
        mmv[i] = v;
        float4 rv;
        rv.x = 1.0f / (v.x + EPS_); rv.y = 1.0f / (v.y + EPS_);
        rv.z = 1.0f / (v.z + EPS_); rv.w = 1.0f / (v.w + EPS_);
        rcv[i] = rv;
    }
}

__global__ __launch_bounds__(256) void k3_norm(const float* __restrict__ mag,
                                               const float* __restrict__ recip,
                                               float* __restrict__ out) {
    __shared__ float4 rec4[T4];
    const int blk = blockIdx.x;
    const int b   = blk / 33;
    const int ch  = blk % 33;
    const int tid = threadIdx.x;

    {
        const float4* rcv = reinterpret_cast<const float4*>(recip) + (size_t)b * T4;
        for (int i = tid; i < T4; i += 256) rec4[i] = rcv[i];
    }
    __syncthreads();

    const bool has2 = tid < (T4 - 512);
    const float4 r0 = rec4[tid];
    const float4 r1 = rec4[tid + 256];
    const float4 r2 = has2 ? rec4[tid + 512] : r0;

    const int f0 = ch * 8;
    const int nr = (ch == 32) ? 1 : 8;
    const float4* magv = reinterpret_cast<const float4*>(mag)
                       + ((size_t)(b * F_ + f0)) * T4;
    float4* ov = reinterpret_cast<float4*>(out)
               + ((size_t)(b * F_ + f0)) * T4;

    for (int r = 0; r < nr; ++r) {
        const float4* row  = magv + (size_t)r * T4;
        float4*       orow = ov   + (size_t)r * T4;
        float4 v0 = row[tid];
        float4 v1 = row[tid + 256];
        float4 o;
        o.x = v0.x * r0.x; o.y = v0.y * r0.y; o.z = v0.z * r0.z; o.w = v0.w * r0.w;
        orow[tid] = o;
        o.x = v1.x * r1.x; o.y = v1.y * r1.y; o.z = v1.z * r1.z; o.w = v1.w * r1.w;
        orow[tid + 256] = o;
        if (has2) {
            float4 v2 = row[tid + 512];
            o.x = v2.x * r2.x; o.y = v2.y * r2.y; o.z = v2.z * r2.z; o.w = v2.w * r2.w;
            orow[tid + 512] = o;
        }
    }
}

extern "C" void kernel_launch(void* const* d_in, const int* in_sizes, int n_in,
                              void* d_out, int out_size, void* d_ws, size_t ws_size,
                              hipStream_t stream) {
    (void)in_sizes; (void)n_in; (void)out_size;
    const float* mag   = (const float*)d_in[0];
    const float* bias  = (const float*)d_in[1];
    const float* rmean = (const float*)d_in[2];
    float* out      = (float*)d_out;
    float* mag_mean = out + (size_t)B_ * F_ * T_;       // second tuple output

    // one-pass layout: [flag1 1024u][flag2 32u][pad->8KB][partial 12.29MB][recip 384KB]
    const size_t flags_bytes   = 8192;
    const size_t partial_elems = (size_t)B_ * 32 * T_;  // 3,072,000 floats
    const size_t recip_elems   = (size_t)B_ * T_;
    const size_t need_onepass  = flags_bytes
                               + partial_elems * sizeof(float)
                               + recip_elems * sizeof(float); // ~12.68 MB

    if (ws_size >= need_onepass) {
        unsigned* flag1 = (unsigned*)d_ws;
        unsigned* flag2 = flag1 + 1024;
        float* partial  = (float*)((char*)d_ws + flags_bytes);
        float* recip    = partial + partial_elems;
        hipMemsetAsync(d_ws, 0, flags_bytes, stream);
        ema_onepass<<<B_ * 32, 256, 0, stream>>>(mag, bias, rmean, out, mag_mean,
                                                 flag1, flag2, partial, recip);
        return;
    }

    // fallback: proven R7 pipeline
    float* recip = (float*)d_ws;                        // 384 KB
    const size_t recip_sz   = (size_t)B_ * T_ * sizeof(float);
    const size_t partial_sz = (size_t)B_ * NG1 * T_ * sizeof(float);  // 6.14 MB

    if (ws_size >= recip_sz + partial_sz) {
        float* partial = recip + (size_t)B_ * T_;
        k1_partial<<<B_ * NG1, 256, 0, stream>>>(mag, partial);
        k_reduce_scan<<<B_, 256, 0, stream>>>(partial, NG1, bias, rmean,
                                              recip, mag_mean);
    } else {
        k_reduce_scan<<<B_, 256, 0, stream>>>(mag, F_, bias, rmean,
                                              recip, mag_mean);
    }
    k3_norm<<<B_ * 33, 256, 0, stream>>>(mag, recip, out);
}

// Round 6
// 207.078 us; speedup vs baseline: 2.8831x; 2.8831x over previous
//
#include <hip/hip_runtime.h>

// EMA energy normalizer: mag [B,F,T] fp32 -> (mag_norm [B,F,T], mag_mean [B,1,T])
//
// R9 (resubmit — R5 bench was a broker timeout, no data): FLAGLESS,
// SPILL-LESS two-kernel pipeline.
// Post-mortem trail:
//  - R6 (one-pass, flags, columnar): 352us. Gathers ~175us + ~170us unexplained
//    -> spin/acquire-invalidate storms now the prime suspect for the rest.
//  - R7 (3-kernel, flagless, linear): 206us total, ~73us ours. PROVEN.
//  - R8 (one-pass, flags, reg-held rows): 510us. VGPR=76 proves r[8][3]
//    spilled to scratch (~100MB private round-trip); flags + spill both bad.
// R9 = R7 minus its slack: drop the separate 32-block KRS dispatch + drain +
// recip round-trip by RECOMPUTING the scan redundantly in each normalize
// block (R5-validated pattern). Two dispatches, no atomics, nothing held in
// registers across phases. mag's 2nd read is L3-warm (98.7MB < 256MB L3).
//   K1 (512 blocks):  16-17 full rows -> register-accumulated partial row.
//   K2 (1056 blocks): reduce 16 partial rows (L2/L3-hit) -> frame means in
//                     LDS -> affine Hillis-Steele scan -> recips in LDS ->
//                     stream-normalize 8 rows. ch==0 writes mag_mean.

#define B_   32
#define F_   257
#define T_   3000
#define T4   750          // float4s per row
#define NG1  16           // partial rows per batch; g==15 folds row 256
#define MOM  0.99f
#define OMM  0.01f
#define EPS_ 1e-8f
#define INVF (1.0f / 257.0f)

#define ACC4(a, v) { a.x += v.x; a.y += v.y; a.z += v.z; a.w += v.w; }

// ---------------------------------------------------------------------------
// K1: block (b, g) reduces rows [g*16, g*16+nr) of batch b into one partial
// row. Thread owns float4 columns {tid, tid+256, tid+512}; every load is a
// wave-contiguous 1 KB run; rows are read fully linearly. (Proven in R7.)
// ---------------------------------------------------------------------------
__global__ __launch_bounds__(256) void k1_partial(const float* __restrict__ mag,
                                                  float* __restrict__ partial) {
    const int blk = blockIdx.x;          // b*16 + g
    const int b   = blk >> 4;
    const int g   = blk & 15;
    const int tid = threadIdx.x;
    const bool has2 = tid < (T4 - 512);  // tid < 238 owns a third column

    const float4* magv = reinterpret_cast<const float4*>(mag)
                       + ((size_t)(b * F_ + g * 16)) * T4;
    float4 a0 = make_float4(0.f,0.f,0.f,0.f);
    float4 a1 = make_float4(0.f,0.f,0.f,0.f);
    float4 a2 = make_float4(0.f,0.f,0.f,0.f);

    #pragma unroll 4
    for (int r = 0; r < 16; ++r) {
        const float4* row = magv + (size_t)r * T4;
        float4 v0 = row[tid];
        float4 v1 = row[tid + 256];
        ACC4(a0, v0);
        ACC4(a1, v1);
        if (has2) { float4 v2 = row[tid + 512]; ACC4(a2, v2); }
    }
    if (g == 15) {                       // row 256 (the odd one out)
        const float4* row = magv + (size_t)16 * T4;
        float4 v0 = row[tid];
        float4 v1 = row[tid + 256];
        ACC4(a0, v0);
        ACC4(a1, v1);
        if (has2) { float4 v2 = row[tid + 512]; ACC4(a2, v2); }
    }

    float4* pv = reinterpret_cast<float4*>(partial) + (size_t)blk * T4;
    pv[tid]       = a0;
    pv[tid + 256] = a1;
    if (has2) pv[tid + 512] = a2;
}

// ---------------------------------------------------------------------------
// K2: block (b, ch) — redundant per-block {reduce partials + scan}, then
// stream-normalize rows [ch*8, ch*8+nr). All global access linear.
// ---------------------------------------------------------------------------
__global__ __launch_bounds__(256) void k2_scan_norm(
    const float* __restrict__ partial,
    const float* __restrict__ bias,
    const float* __restrict__ rmean,
    const float* __restrict__ mag,
    float* __restrict__ out,
    float* __restrict__ mag_mean)
{
    __shared__ float4 xs4[T4];           // 12 KB: means -> mean+bias -> recips
    float* xs = reinterpret_cast<float*>(xs4);
    __shared__ float sA[256];
    __shared__ float sB[256];

    const int blk = blockIdx.x;          // b*33 + ch
    const int b   = blk / 33;
    const int ch  = blk % 33;
    const int tid = threadIdx.x;
    const bool c2 = tid < (T4 - 512);

    // ---- reduce the 16 partial rows (L2/L3-resident, 192 KB) -> frame means
    {
        const float4* pv = reinterpret_cast<const float4*>(partial)
                         + (size_t)b * NG1 * T4;
        float4 s0 = make_float4(0.f,0.f,0.f,0.f);
        float4 s1 = make_float4(0.f,0.f,0.f,0.f);
        float4 s2 = make_float4(0.f,0.f,0.f,0.f);
        #pragma unroll 4
        for (int r = 0; r < NG1; ++r) {
            const float4* rp = pv + (size_t)r * T4;
            float4 v0 = rp[tid];
            float4 v1 = rp[tid + 256];
            ACC4(s0, v0);
            ACC4(s1, v1);
            if (c2) { float4 v2 = rp[tid + 512]; ACC4(s2, v2); }
        }
        s0.x *= INVF; s0.y *= INVF; s0.z *= INVF; s0.w *= INVF;
        s1.x *= INVF; s1.y *= INVF; s1.z *= INVF; s1.w *= INVF;
        xs4[tid]       = s0;
        xs4[tid + 256] = s1;
        if (c2) {
            s2.x *= INVF; s2.y *= INVF; s2.z *= INVF; s2.w *= INVF;
            xs4[tid + 512] = s2;
        }
    }
    __syncthreads();

    // ---- local chunk scan: 250 active threads x 12 steps (validated)
    const int CH = 12;
    const int t0 = tid * CH;
    float A = 1.f, Bv = 0.f;
    if (t0 < T_) {
        #pragma unroll
        for (int j = 0; j < CH; ++j) {
            Bv = MOM * Bv + OMM * xs[t0 + j];
            A *= MOM;
        }
    }
    sA[tid] = A; sB[tid] = Bv;
    __syncthreads();

    // Hillis-Steele over affine maps: (Ap,Bp)∘(Ac,Bc) = (Ap*Ac, Bp*Ac+Bc)
    for (int off = 1; off < 256; off <<= 1) {
        float cA = sA[tid], cB = sB[tid];
        float pA = 1.f, pB = 0.f;
        if (tid >= off) { pA = sA[tid - off]; pB = sB[tid - off]; }
        __syncthreads();
        if (tid >= off) { sA[tid] = pA * cA; sB[tid] = pB * cA + cB; }
        __syncthreads();
    }
    float pA = 1.f, pB = 0.f;
    if (tid > 0) { pA = sA[tid - 1]; pB = sB[tid - 1]; }
    __syncthreads();

    const float bias0 = bias[0];
    if (t0 < T_) {
        float m = pA * rmean[0] + pB;        // m_{t0-1}
        #pragma unroll
        for (int j = 0; j < CH; ++j) {
            m = MOM * m + OMM * xs[t0 + j];
            xs[t0 + j] = m + bias0;          // mean + bias
        }
    }
    __syncthreads();

    // ---- ch==0 emits mag_mean; everyone flips xs to reciprocals
    if (ch == 0) {
        float4* mmv = reinterpret_cast<float4*>(mag_mean) + (size_t)b * T4;
        for (int i = tid; i < T4; i += 256) mmv[i] = xs4[i];
    }
    for (int i = tid; i < T4; i += 256) {
        float4 v = xs4[i];
        v.x = 1.0f / (v.x + EPS_); v.y = 1.0f / (v.y + EPS_);
        v.z = 1.0f / (v.z + EPS_); v.w = 1.0f / (v.w + EPS_);
        xs4[i] = v;
    }
    __syncthreads();

    // ---- stream-normalize rows [f0, f0+nr): recips in registers, linear IO
    const float4 r0 = xs4[tid];
    const float4 r1 = xs4[tid + 256];
    const float4 r2 = c2 ? xs4[tid + 512] : r0;

    const int f0 = ch * 8;
    const int nr = (ch == 32) ? 1 : 8;
    const float4* magv = reinterpret_cast<const float4*>(mag)
                       + ((size_t)(b * F_ + f0)) * T4;
    float4* ov = reinterpret_cast<float4*>(out)
               + ((size_t)(b * F_ + f0)) * T4;

    for (int r = 0; r < nr; ++r) {
        const float4* row  = magv + (size_t)r * T4;
        float4*       orow = ov   + (size_t)r * T4;
        float4 v0 = row[tid];
        float4 v1 = row[tid + 256];
        float4 o;
        o.x = v0.x * r0.x; o.y = v0.y * r0.y; o.z = v0.z * r0.z; o.w = v0.w * r0.w;
        orow[tid] = o;
        o.x = v1.x * r1.x; o.y = v1.y * r1.y; o.z = v1.z * r1.z; o.w = v1.w * r1.w;
        orow[tid + 256] = o;
        if (c2) {
            float4 v2 = row[tid + 512];
            o.x = v2.x * r2.x; o.y = v2.y * r2.y; o.z = v2.z * r2.z; o.w = v2.w * r2.w;
            orow[tid + 512] = o;
        }
    }
}

// ---------------------------------------------------------------------------
// Fallback (tiny ws): reduce mag directly in one fat kernel per batch, then
// normalize. Needs only 384 KB. (R7 path B, proven code.)
// ---------------------------------------------------------------------------
__global__ __launch_bounds__(256) void k_reduce_scan(const float* __restrict__ src,
                                                     int nrows,
                                                     const float* __restrict__ bias,
                                                     const float* __restrict__ rmean,
                                                     float* __restrict__ recip,
                                                     float* __restrict__ mag_mean) {
    __shared__ float4 xs4[T4];
    float* xs = reinterpret_cast<float*>(xs4);
    __shared__ float sA[256];
    __shared__ float sB[256];

    const int b   = blockIdx.x;
    const int tid = threadIdx.x;
    const bool has2 = tid < (T4 - 512);

    {
        const float4* sv = reinterpret_cast<const float4*>(src)
                         + (size_t)b * nrows * T4;
        float4 a0 = make_float4(0.f,0.f,0.f,0.f);
        float4 a1 = make_float4(0.f,0.f,0.f,0.f);
        float4 a2 = make_float4(0.f,0.f,0.f,0.f);
        #pragma unroll 4
        for (int r = 0; r < nrows; ++r) {
            const float4* row = sv + (size_t)r * T4;
            float4 v0 = row[tid];
            float4 v1 = row[tid + 256];
            ACC4(a0, v0); ACC4(a1, v1);
            if (has2) { float4 v2 = row[tid + 512]; ACC4(a2, v2); }
        }
        a0.x *= INVF; a0.y *= INVF; a0.z *= INVF; a0.w *= INVF;
        a1.x *= INVF; a1.y *= INVF; a1.z *= INVF; a1.w *= INVF;
        xs4[tid]       = a0;
        xs4[tid + 256] = a1;
        if (has2) {
            a2.x *= INVF; a2.y *= INVF; a2.z *= INVF; a2.w *= INVF;
            xs4[tid + 512] = a2;
        }
    }
    __syncthreads();

    const int CH = 12;
    const int t0 = tid * CH;
    float A = 1.f, Bv = 0.f;
    if (t0 < T_) {
        #pragma unroll
        for (int j = 0; j < CH; ++j) {
            Bv = MOM * Bv + OMM * xs[t0 + j];
            A *= MOM;
        }
    }
    sA[tid] = A; sB[tid] = Bv;
    __syncthreads();

    for (int off = 1; off < 256; off <<= 1) {
        float cA = sA[tid], cB = sB[tid];
        float pA = 1.f, pB = 0.f;
        if (tid >= off) { pA = sA[tid - off]; pB = sB[tid - off]; }
        __syncthreads();
        if (tid >= off) { sA[tid] = pA * cA; sB[tid] = pB * cA + cB; }
        __syncthreads();
    }
    float pA = 1.f, pB = 0.f;
    if (tid > 0) { pA = sA[tid - 1]; pB = sB[tid - 1]; }
    __syncthreads();

    const float bias0 = bias[0];
    if (t0 < T_) {
        float m = pA * rmean[0] + pB;
        #pragma unroll
        for (int j = 0; j < CH; ++j) {
            m = MOM * m + OMM * xs[t0 + j];
            xs[t0 + j] = m + bias0;
        }
    }
    __syncthreads();

    float4* mmv = reinterpret_cast<float4*>(mag_mean) + (size_t)b * T4;
    float4* rcv = reinterpret_cast<float4*>(recip)    + (size_t)b * T4;
    for (int i = tid; i < T4; i += 256) {
        float4 v = xs4[i];
        mmv[i] = v;
        float4 rv;
        rv.x = 1.0f / (v.x + EPS_); rv.y = 1.0f / (v.y + EPS_);
        rv.z = 1.0f / (v.z + EPS_); rv.w = 1.0f / (v.w + EPS_);
        rcv[i] = rv;
    }
}

__global__ __launch_bounds__(256) void k3_norm(const float* __restrict__ mag,
                                               const float* __restrict__ recip,
                                               float* __restrict__ out) {
    __shared__ float4 rec4[T4];
    const int blk = blockIdx.x;
    const int b   = blk / 33;
    const int ch  = blk % 33;
    const int tid = threadIdx.x;

    {
        const float4* rcv = reinterpret_cast<const float4*>(recip) + (size_t)b * T4;
        for (int i = tid; i < T4; i += 256) rec4[i] = rcv[i];
    }
    __syncthreads();

    const bool has2 = tid < (T4 - 512);
    const float4 r0 = rec4[tid];
    const float4 r1 = rec4[tid + 256];
    const float4 r2 = has2 ? rec4[tid + 512] : r0;

    const int f0 = ch * 8;
    const int nr = (ch == 32) ? 1 : 8;
    const float4* magv = reinterpret_cast<const float4*>(mag)
                       + ((size_t)(b * F_ + f0)) * T4;
    float4* ov = reinterpret_cast<float4*>(out)
               + ((size_t)(b * F_ + f0)) * T4;

    for (int r = 0; r < nr; ++r) {
        const float4* row  = magv + (size_t)r * T4;
        float4*       orow = ov   + (size_t)r * T4;
        float4 v0 = row[tid];
        float4 v1 = row[tid + 256];
        float4 o;
        o.x = v0.x * r0.x; o.y = v0.y * r0.y; o.z = v0.z * r0.z; o.w = v0.w * r0.w;
        orow[tid] = o;
        o.x = v1.x * r1.x; o.y = v1.y * r1.y; o.z = v1.z * r1.z; o.w = v1.w * r1.w;
        orow[tid + 256] = o;
        if (has2) {
            float4 v2 = row[tid + 512];
            o.x = v2.x * r2.x; o.y = v2.y * r2.y; o.z = v2.z * r2.z; o.w = v2.w * r2.w;
            orow[tid + 512] = o;
        }
    }
}

extern "C" void kernel_launch(void* const* d_in, const int* in_sizes, int n_in,
                              void* d_out, int out_size, void* d_ws, size_t ws_size,
                              hipStream_t stream) {
    (void)in_sizes; (void)n_in; (void)out_size;
    const float* mag   = (const float*)d_in[0];
    const float* bias  = (const float*)d_in[1];
    const float* rmean = (const float*)d_in[2];
    float* out      = (float*)d_out;
    float* mag_mean = out + (size_t)B_ * F_ * T_;       // second tuple output

    const size_t partial_sz = (size_t)B_ * NG1 * T_ * sizeof(float);  // 6.14 MB
    const size_t recip_sz   = (size_t)B_ * T_ * sizeof(float);        // 384 KB

    if (ws_size >= partial_sz) {
        // Main path (R9): two dispatches, flagless, redundant per-block scan.
        float* partial = (float*)d_ws;
        k1_partial<<<B_ * NG1, 256, 0, stream>>>(mag, partial);
        k2_scan_norm<<<B_ * 33, 256, 0, stream>>>(partial, bias, rmean, mag,
                                                  out, mag_mean);
    } else {
        // Fallback: direct reduce from mag (32 fat blocks) + normalize.
        float* recip = (float*)d_ws;                    // 384 KB
        k_reduce_scan<<<B_, 256, 0, stream>>>(mag, F_, bias, rmean,
                                              recip, mag_mean);
        k3_norm<<<B_ * 33, 256, 0, stream>>>(mag, recip, out);
    }
}